// Round 5
// baseline (290.489 us; speedup 1.0000x reference)
//
#include <hip/hip_runtime.h>
#include <stdint.h>

#define NB 8
#define CC 512
#define LL 3136
#define CIN 256

typedef __attribute__((ext_vector_type(8))) short bf8;
typedef __attribute__((ext_vector_type(4))) float f4;
typedef __attribute__((ext_vector_type(16))) float f16v;
typedef __attribute__((ext_vector_type(4))) int i4;

__device__ __forceinline__ f4 mfma_bf16(bf8 a, bf8 b, f4 c) {
  return __builtin_amdgcn_mfma_f32_16x16x32_bf16(a, b, c, 0, 0, 0);
}

__device__ __forceinline__ f16v mfma32(bf8 a, bf8 b, f16v c) {
  return __builtin_amdgcn_mfma_f32_32x32x16_bf16(a, b, c, 0, 0, 0);
}

__device__ __forceinline__ unsigned short f2bf(float f) {
  unsigned int u = __float_as_uint(f);
  u += 0x7FFFu + ((u >> 16) & 1u);
  return (unsigned short)(u >> 16);
}

// packed f32x2 -> bf16x2 (RNE), low word = lo, high word = hi
__device__ __forceinline__ int cvtpk_bf16(float lo, float hi) {
  int r;
  asm("v_cvt_pk_bf16_f32 %0, %1, %2" : "=v"(r) : "v"(lo), "v"(hi));
  return r;
}

__device__ __forceinline__ void gload_lds16(const unsigned short* g, unsigned short* l) {
  __builtin_amdgcn_global_load_lds(
      (const __attribute__((address_space(1))) void*)g,
      (__attribute__((address_space(3))) void*)l, 16, 0, 0);
}

// ---- kernel 0a: convert weights to bf16. layout: [Wth][Wph][Wg][Wout]
__global__ void k_convw(const float* Wth, const float* Wph, const float* Wg, const float* Wout,
                        unsigned short* dst) {
  int i = blockIdx.x * 256 + threadIdx.x;
  int which = i >> 17;
  int off = i & 131071;
  const float* s = which == 0 ? Wth : which == 1 ? Wph : which == 2 ? Wg : Wout;
  dst[i] = f2bf(s[off]);
}

// ---- kernel 0b: transpose x (n,C,L) fp32 -> xT (n,L,C) bf16, 64x64 tiles
__global__ __launch_bounds__(256) void k_xT(const float* x, unsigned short* xT) {
  __shared__ unsigned short tile[64][66];
  const int lt = blockIdx.x, n = blockIdx.y, ct = blockIdx.z;
  const int t = threadIdx.x;
  const float* xb = x + (size_t)n * CC * LL + (size_t)(ct * 64) * LL + lt * 64;
  const int tl = t & 63, trow = t >> 6;
#pragma unroll
  for (int i = 0; i < 16; ++i) {
    int c = i * 4 + trow;
    tile[c][tl] = f2bf(xb[(size_t)c * LL + tl]);
  }
  __syncthreads();
  unsigned short* xo = xT + (size_t)n * LL * CC + (size_t)(lt * 64) * CC + ct * 64;
  const int tc = t & 63, lrow = t >> 6;
#pragma unroll
  for (int i = 0; i < 16; ++i) {
    int l = i * 4 + lrow;
    xo[(size_t)l * CC + tc] = tile[tc][l];
  }
}

// ---- kernel 1 v3: projections, 128(ci) x 128(L) tiles (was 128x64).
// Per chunk/wave: 32 MFMA vs 20 ds_read_b128 (was 16 vs 12); staging bytes/FLOP x0.67,
// barriers/FLOP x0.5. LDS 64KB -> 2 blocks/CU. Tail L-rows guarded on store;
// tail staging reads land in allocated ws regions (O1/denp).
__global__ __launch_bounds__(256, 2) void k_proj(const unsigned short* Wbf,
    const float* bth, const float* bph, const float* bg,
    const unsigned short* xT, unsigned short* QT, unsigned short* KT, unsigned short* Vb) {
  __shared__ unsigned short wtile[2][8192];   // 128 ci x 64 k
  __shared__ unsigned short xtile[2][8192];   // 128 L  x 64 k
  const int bid = blockIdx.x;
  const int n = bid & 7, t = bid >> 3;
  const int lt = t % 25, z = t / 25;          // lt: 25 tiles of 128 L (3200, tail masked)
  const int proj = z >> 1, cith = z & 1;
  const int tid = threadIdx.x;
  const int wave = tid >> 6, lane = tid & 63;
  const int quad = lane >> 4, c16 = lane & 15;

  const unsigned short* Wg = Wbf + proj * 131072 + (size_t)(cith * 128) * CC;
  const unsigned short* Xg = xT + (size_t)n * LL * CC + (size_t)(lt * 128) * CC;

  auto issue = [&](int chunk, int b) {
    const int cb = chunk * 64;
#pragma unroll
    for (int i = 0; i < 4; ++i) {
      int seg = i * 4 + wave;
      int p = seg * 64 + lane;
      int r = p >> 3, sl = p & 7, g = sl ^ (r & 7);
      gload_lds16(Wg + (size_t)r * CC + cb + g * 8, &wtile[b][seg * 512]);
    }
#pragma unroll
    for (int i = 0; i < 4; ++i) {
      int seg = i * 4 + wave;
      int p = seg * 64 + lane;
      int r = p >> 3, sl = p & 7, g = sl ^ (r & 7);
      gload_lds16(Xg + (size_t)r * CC + cb + g * 8, &xtile[b][seg * 512]);
    }
  };

  const f4 zz = {0.f, 0.f, 0.f, 0.f};
  f4 acc[2][8];
#pragma unroll
  for (int i = 0; i < 2; ++i)
#pragma unroll
    for (int j = 0; j < 8; ++j) acc[i][j] = zz;

  issue(0, 0);
  for (int chunk = 0; chunk < 8; ++chunk) {
    __syncthreads();
    if (chunk + 1 < 8) issue(chunk + 1, (chunk + 1) & 1);
    const int bb = chunk & 1;
#pragma unroll
    for (int kc = 0; kc < 2; ++kc) {
      const int slot = (kc * 4 + quad) ^ (c16 & 7);
      bf8 wf[2], xf[8];
#pragma unroll
      for (int sub = 0; sub < 2; ++sub)
        wf[sub] = *(const bf8*)(&wtile[bb][(wave * 32 + sub * 16 + c16) * 64 + slot * 8]);
#pragma unroll
      for (int nt = 0; nt < 8; ++nt)
        xf[nt] = *(const bf8*)(&xtile[bb][(nt * 16 + c16) * 64 + slot * 8]);
      if (proj < 2) {
#pragma unroll
        for (int sub = 0; sub < 2; ++sub)
#pragma unroll
          for (int nt = 0; nt < 8; ++nt)
            acc[sub][nt] = mfma_bf16(wf[sub], xf[nt], acc[sub][nt]);
      } else {
#pragma unroll
        for (int sub = 0; sub < 2; ++sub)
#pragma unroll
          for (int nt = 0; nt < 8; ++nt)
            acc[sub][nt] = mfma_bf16(xf[nt], wf[sub], acc[sub][nt]);
      }
    }
  }

  if (proj < 2) {
    const float* bias = proj == 0 ? bth : bph;
    unsigned short* dst = proj == 0 ? QT : KT;
#pragma unroll
    for (int sub = 0; sub < 2; ++sub) {
      const int ciB = cith * 128 + wave * 32 + sub * 16 + quad * 4;
      const float b0 = bias[ciB + 0], b1 = bias[ciB + 1];
      const float b2 = bias[ciB + 2], b3 = bias[ciB + 3];
#pragma unroll
      for (int nt = 0; nt < 8; ++nt) {
        int l = lt * 128 + nt * 16 + c16;
        if (l < LL) {
          ushort4 v;
          v.x = f2bf(acc[sub][nt][0] + b0);
          v.y = f2bf(acc[sub][nt][1] + b1);
          v.z = f2bf(acc[sub][nt][2] + b2);
          v.w = f2bf(acc[sub][nt][3] + b3);
          *(ushort4*)(dst + ((size_t)n * LL + l) * CIN + ciB) = v;
        }
      }
    }
  } else {
#pragma unroll
    for (int sub = 0; sub < 2; ++sub) {
      const int ci = cith * 128 + wave * 32 + sub * 16 + c16;
      const float bv = bg[ci];
#pragma unroll
      for (int nt = 0; nt < 8; ++nt) {
        int l = lt * 128 + nt * 16 + quad * 4;
        if (l < LL) {
          ushort4 v;
          v.x = f2bf(acc[sub][nt][0] + bv);
          v.y = f2bf(acc[sub][nt][1] + bv);
          v.z = f2bf(acc[sub][nt][2] + bv);
          v.w = f2bf(acc[sub][nt][3] + bv);
          *(ushort4*)(Vb + ((size_t)n * CIN + ci) * LL + l) = v;
        }
      }
    }
  }
}

// ---- kernel 2 v9: flash attention (unchanged): swapped QK^T, in-register
// softmax (T12), s_setprio around MFMA clusters (T5).
__global__ __launch_bounds__(256, 2) void k_attn(const unsigned short* QT, const unsigned short* KT,
                                                 const unsigned short* Vb, unsigned short* Opart,
                                                 float* denp) {
  __shared__ unsigned short kbuf[2][8192];   // 32 keys x 256 shorts, granule slot = g ^ row
  __shared__ unsigned short vbuf[2][8192];   // 256 ci x 32 shorts, slot = g ^ ((row>>1)&3)
  const int bid = blockIdx.x;
  const int n = bid & 7, ks = (bid >> 3) & 1, qb = bid >> 4;
  const int tid = threadIdx.x;
  const int wave = tid >> 6, lane = tid & 63;
  const int l31 = lane & 31, half = lane >> 5;
  int q0 = qb * 128 + wave * 32;
  const bool do_store = q0 < LL;
  if (q0 > LL - 32) q0 = LL - 32;      // tail: waves 2,3 duplicate wave-1 rows, stores masked
  const unsigned short* Qb = QT + ((size_t)n * LL + q0) * CIN;
  const unsigned short* Kks = KT + (size_t)n * LL * CIN + (size_t)(ks * 49 * 32) * CIN;
  const unsigned short* Vks = Vb + (size_t)n * CIN * LL + ks * 49 * 32;

  // Q fragments (m=l31, k=kc*16+half*8+j), softmax scale folded.
  const float qs = 0.09016844005556021f;   // log2(e)/16
  bf8 qf[16];
#pragma unroll
  for (int kc = 0; kc < 16; ++kc) {
    bf8 q = *(const bf8*)(Qb + (size_t)l31 * CIN + kc * 16 + half * 8);
#pragma unroll
    for (int e = 0; e < 8; ++e) {
      float f = __uint_as_float(((unsigned)(unsigned short)q[e]) << 16) * qs;
      q[e] = (short)f2bf(f);
    }
    qf[kc] = q;
  }

  f16v o[8];
#pragma unroll
  for (int t = 0; t < 8; ++t)
#pragma unroll
    for (int r = 0; r < 16; ++r) o[t][r] = 0.f;
  float sden = 0.f;   // per-lane partial denominator for q-row l31 (this lane's key set)

  auto issue = [&](int kt, int b) {
    const int k0 = kt * 32;
    const unsigned short* Kg = Kks + (size_t)k0 * CIN;
    const unsigned short* Vg = Vks + k0;
#pragma unroll
    for (int i = 0; i < 4; ++i) {
      int seg = i * 4 + wave;
      int idx = seg * 64 + lane;
      {
        int r = idx >> 5, sl = idx & 31, g = sl ^ r;
        gload_lds16(Kg + r * CIN + g * 8, &kbuf[b][seg * 512]);
      }
      {
        int r = idx >> 2, sl = idx & 3, g = sl ^ ((r >> 1) & 3);
        gload_lds16(Vg + (size_t)r * LL + g * 8, &vbuf[b][seg * 512]);
      }
    }
  };

  issue(0, 0);
  for (int kt = 0; kt < 49; ++kt) {
    __syncthreads();                   // tile kt resident; prev compute done
    if (kt + 1 < 49) issue(kt + 1, (kt + 1) & 1);
    const int b = kt & 1;
    const unsigned short* kb = &kbuf[b][0];
    const unsigned short* vbp = &vbuf[b][0];

    // S^T = K Q^T : A-frag key row = l31 (granule g = kc*2+half, slot = g ^ l31),
    // B-frag = qf. C layout: col = q = l31, row = key kr(r,half)=(r&3)+8*(r>>2)+4*half.
    f16v sc;
#pragma unroll
    for (int r = 0; r < 16; ++r) sc[r] = 0.f;
    __builtin_amdgcn_s_setprio(1);
#pragma unroll
    for (int kc = 0; kc < 16; ++kc) {
      int slot = (kc * 2 + half) ^ l31;
      bf8 kf = *(const bf8*)(kb + l31 * 256 + slot * 8);
      sc = mfma32(kf, qf[kc], sc);
    }
    __builtin_amdgcn_s_setprio(0);

    // Per 16-key chunk m: exp2 -> denominator tree -> cvtpk/permlane -> af[m].
    bf8 af[2];
#pragma unroll
    for (int m = 0; m < 2; ++m) {
      float p0 = __builtin_amdgcn_exp2f(sc[8 * m + 0]);
      float p1 = __builtin_amdgcn_exp2f(sc[8 * m + 1]);
      float p2 = __builtin_amdgcn_exp2f(sc[8 * m + 2]);
      float p3 = __builtin_amdgcn_exp2f(sc[8 * m + 3]);
      float p4 = __builtin_amdgcn_exp2f(sc[8 * m + 4]);
      float p5 = __builtin_amdgcn_exp2f(sc[8 * m + 5]);
      float p6 = __builtin_amdgcn_exp2f(sc[8 * m + 6]);
      float p7 = __builtin_amdgcn_exp2f(sc[8 * m + 7]);
      sden += ((p0 + p1) + (p2 + p3)) + ((p4 + p5) + (p6 + p7));
      int x0 = cvtpk_bf16(p0, p1);
      int y0 = cvtpk_bf16(p4, p5);
      int x1 = cvtpk_bf16(p2, p3);
      int y1 = cvtpk_bf16(p6, p7);
      asm("v_permlane32_swap_b32 %0, %1" : "+v"(x0), "+v"(y0));
      asm("v_permlane32_swap_b32 %0, %1" : "+v"(x1), "+v"(y1));
      i4 w;
      w[0] = x0; w[1] = x1; w[2] = y0; w[3] = y1;
      af[m] = *(bf8*)&w;
    }

    // O += P V : V row = t*32+l31 (ci), granule g = kc2*2+half, slot = g ^ ((l31>>1)&3)
    __builtin_amdgcn_s_setprio(1);
#pragma unroll
    for (int t = 0; t < 8; ++t) {
#pragma unroll
      for (int kc2 = 0; kc2 < 2; ++kc2) {
        int slot = (kc2 * 2 + half) ^ ((l31 >> 1) & 3);
        bf8 v = *(const bf8*)(vbp + (t * 32 + l31) * 32 + slot * 8);
        o[t] = mfma32(af[kc2], v, o[t]);
      }
    }
    __builtin_amdgcn_s_setprio(0);
  }

  // combine the two key-half partial denominators; lane l31 (both halves) holds den[row l31]
  sden += __shfl_xor(sden, 32);

  if (do_store) {
    if (lane < 32) denp[((size_t)ks * NB + n) * LL + q0 + l31] = sden;
    unsigned short* Ob = Opart + (((size_t)ks * NB + n) * LL + q0) * CIN;
#pragma unroll
    for (int t = 0; t < 8; ++t)
#pragma unroll
      for (int r = 0; r < 16; ++r) {
        int row = (r & 3) + 8 * (r >> 2) + 4 * half;
        Ob[(size_t)row * CIN + t * 32 + l31] = f2bf(o[t][r]);
      }
  }
}

// ---- kernel 2b: invden = 1/(den0+den1), NB*LL elements
__global__ void k_den(const float* denp, float* invden) {
  int i = blockIdx.x * 256 + threadIdx.x;
  if (i < NB * LL) invden[i] = 1.f / (denp[i] + denp[NB * LL + i]);
}

// ---- kernel 3 v4: out = x + b_out + Wout @ ((O0+O1)*invden), 128(c) x 128(L) tiles.
__global__ __launch_bounds__(256, 2) void k_out(const unsigned short* O0, const unsigned short* O1,
    const unsigned short* Wo, const float* bout, const float* invden,
    const float* x, float* out) {
  __shared__ unsigned short wtile[2][8192];   // 128 c x 64 kci
  __shared__ unsigned short otile[2][8192];   // 128 L x 64 kci
  const int bid = blockIdx.x;
  const int n = bid & 7, t = bid >> 3;
  const int lt = t % 25, cth = t / 25;        // lt: 25 tiles of 128 L; cth < 4
  const int tid = threadIdx.x;
  const int wave = tid >> 6, lane = tid & 63;
  const int quad = lane >> 4, c16 = lane & 15;

  const unsigned short* Wg = Wo + (size_t)(cth * 128) * CIN;
  const unsigned short* Og0 = O0 + ((size_t)n * LL + lt * 128) * CIN;
  const unsigned short* Og1 = O1 + ((size_t)n * LL + lt * 128) * CIN;

  auto issue = [&](int chunk, int b) {
    const int cb = (chunk & 3) * 64;
    const unsigned short* Og = chunk < 4 ? Og0 : Og1;
#pragma unroll
    for (int i = 0; i < 4; ++i) {
      int seg = i * 4 + wave;
      int p = seg * 64 + lane;
      int r = p >> 3, sl = p & 7, g = sl ^ (r & 7);
      gload_lds16(Wg + (size_t)r * CIN + cb + g * 8, &wtile[b][seg * 512]);
    }
#pragma unroll
    for (int i = 0; i < 4; ++i) {
      int seg = i * 4 + wave;
      int p = seg * 64 + lane;
      int r = p >> 3, sl = p & 7, g = sl ^ (r & 7);
      gload_lds16(Og + (size_t)r * CIN + cb + g * 8, &otile[b][seg * 512]);
    }
  };

  const f4 zz = {0.f, 0.f, 0.f, 0.f};
  f4 acc[8][2];
#pragma unroll
  for (int i = 0; i < 8; ++i)
#pragma unroll
    for (int j = 0; j < 2; ++j) acc[i][j] = zz;

  issue(0, 0);
  for (int chunk = 0; chunk < 8; ++chunk) {
    __syncthreads();
    if (chunk + 1 < 8) issue(chunk + 1, (chunk + 1) & 1);
    const int bb = chunk & 1;
#pragma unroll
    for (int kc = 0; kc < 2; ++kc) {
      const int slot = (kc * 4 + quad) ^ (c16 & 7);
      bf8 wf[2], ofr[8];
#pragma unroll
      for (int sub = 0; sub < 2; ++sub)
        wf[sub] = *(const bf8*)(&wtile[bb][(wave * 32 + sub * 16 + c16) * 64 + slot * 8]);
#pragma unroll
      for (int nt = 0; nt < 8; ++nt)
        ofr[nt] = *(const bf8*)(&otile[bb][(nt * 16 + c16) * 64 + slot * 8]);
#pragma unroll
      for (int nt = 0; nt < 8; ++nt)
#pragma unroll
        for (int sub = 0; sub < 2; ++sub)
          acc[nt][sub] = mfma_bf16(ofr[nt], wf[sub], acc[nt][sub]);
    }
  }

#pragma unroll
  for (int sub = 0; sub < 2; ++sub) {
    const int c = cth * 128 + wave * 32 + sub * 16 + c16;
    const float bv = bout[c];
#pragma unroll
    for (int nt = 0; nt < 8; ++nt) {
      int l = lt * 128 + nt * 16 + quad * 4;
      if (l < LL) {
        f4 iv = *(const f4*)(invden + (size_t)n * LL + l);
        size_t base = ((size_t)n * CC + c) * LL + l;
        f4 xv = *(const f4*)(x + base);
        f4 r;
        r[0] = xv[0] + bv + acc[nt][sub][0] * iv[0];
        r[1] = xv[1] + bv + acc[nt][sub][1] * iv[1];
        r[2] = xv[2] + bv + acc[nt][sub][2] * iv[2];
        r[3] = xv[3] + bv + acc[nt][sub][3] * iv[3];
        *(f4*)(out + base) = r;
      }
    }
  }
}

extern "C" void kernel_launch(void* const* d_in, const int* in_sizes, int n_in,
                              void* d_out, int out_size, void* d_ws, size_t ws_size,
                              hipStream_t stream) {
  const float* x     = (const float*)d_in[0];
  const float* W_g   = (const float*)d_in[1];
  const float* b_g   = (const float*)d_in[2];
  const float* W_th  = (const float*)d_in[3];
  const float* b_th  = (const float*)d_in[4];
  const float* W_ph  = (const float*)d_in[5];
  const float* b_ph  = (const float*)d_in[6];
  const float* W_out = (const float*)d_in[7];
  const float* b_out = (const float*)d_in[8];

  char* ws = (char*)d_ws;
  const size_t SZ_W  = 1048576;            // 4 x 131072 bf16
  const size_t SZ_P  = 12845056;           // 8*3136*256*2 bytes
  unsigned short* Wbf = (unsigned short*)(ws);
  unsigned short* QT  = (unsigned short*)(ws + SZ_W);
  unsigned short* KT  = (unsigned short*)(ws + SZ_W + SZ_P);
  unsigned short* Vb  = (unsigned short*)(ws + SZ_W + 2 * SZ_P);
  unsigned short* xT  = (unsigned short*)(ws + SZ_W + 3 * SZ_P);   // 2*SZ_P bytes
  unsigned short* O0  = xT;                 // alias: xT dead after k_proj
  unsigned short* O1  = (unsigned short*)(ws + SZ_W + 4 * SZ_P);
  float* denp   = (float*)(ws + SZ_W + 5 * SZ_P);                  // 2*NB*LL fp32
  float* invden = (float*)(ws + SZ_W + 5 * SZ_P + 2 * NB * LL * 4);
  float* out = (float*)d_out;

  k_convw<<<2048, 256, 0, stream>>>(W_th, W_ph, W_g, W_out, Wbf);
  k_xT<<<dim3(49, 8, 8), 256, 0, stream>>>(x, xT);
  k_proj<<<1200, 256, 0, stream>>>(Wbf, b_th, b_ph, b_g, xT, QT, KT, Vb);
  k_attn<<<400, 256, 0, stream>>>(QT, KT, Vb, O0, denp);
  k_den<<<98, 256, 0, stream>>>(denp, invden);
  k_out<<<800, 256, 0, stream>>>(O0, O1, Wbf + 3 * 131072, b_out, invden, x, out);
}

// Round 6
// 279.288 us; speedup vs baseline: 1.0401x; 1.0401x over previous
//
#include <hip/hip_runtime.h>
#include <stdint.h>

#define NB 8
#define CC 512
#define LL 3136
#define CIN 256

typedef __attribute__((ext_vector_type(8))) short bf8;
typedef __attribute__((ext_vector_type(4))) float f4;
typedef __attribute__((ext_vector_type(16))) float f16v;
typedef __attribute__((ext_vector_type(4))) int i4;

__device__ __forceinline__ f4 mfma_bf16(bf8 a, bf8 b, f4 c) {
  return __builtin_amdgcn_mfma_f32_16x16x32_bf16(a, b, c, 0, 0, 0);
}

__device__ __forceinline__ f16v mfma32(bf8 a, bf8 b, f16v c) {
  return __builtin_amdgcn_mfma_f32_32x32x16_bf16(a, b, c, 0, 0, 0);
}

__device__ __forceinline__ unsigned short f2bf(float f) {
  unsigned int u = __float_as_uint(f);
  u += 0x7FFFu + ((u >> 16) & 1u);
  return (unsigned short)(u >> 16);
}

// packed f32x2 -> bf16x2 (RNE), low word = lo, high word = hi
__device__ __forceinline__ int cvtpk_bf16(float lo, float hi) {
  int r;
  asm("v_cvt_pk_bf16_f32 %0, %1, %2" : "=v"(r) : "v"(lo), "v"(hi));
  return r;
}

__device__ __forceinline__ void gload_lds16(const unsigned short* g, unsigned short* l) {
  __builtin_amdgcn_global_load_lds(
      (const __attribute__((address_space(1))) void*)g,
      (__attribute__((address_space(3))) void*)l, 16, 0, 0);
}

// ---- kernel 0 (merged): weight bf16 convert + x transpose.
// bid <  3136 : transpose x (n,C,L) fp32 -> xT (n,L,C) bf16, 64x64 tile.
//               float4 loads, ushort4 stores (was 16 scalar loads + 16 scalar stores).
// bid >= 3136 : convert weights. layout: [Wth][Wph][Wg][Wout]
__global__ __launch_bounds__(256) void k_cvt(const float* Wth, const float* Wph, const float* Wg,
                                             const float* Wout, unsigned short* Wbf,
                                             const float* x, unsigned short* xT) {
  const int bid = blockIdx.x;
  const int t = threadIdx.x;
  if (bid >= 3136) {                       // ---- weight convert part
    int i = (bid - 3136) * 256 + t;
    int which = i >> 17, off = i & 131071;
    const float* s = which == 0 ? Wth : which == 1 ? Wph : which == 2 ? Wg : Wout;
    Wbf[i] = f2bf(s[off]);
    return;
  }
  // ---- transpose part
  __shared__ unsigned short tile[64][66];
  const int lt = bid % 49;
  const int rest = bid / 49;
  const int n = rest & 7, ct = rest >> 3;
  const float* xb = x + (size_t)n * CC * LL + (size_t)(ct * 64) * LL + lt * 64;
  {
    const int lq = t & 15, cr = t >> 4;      // lq: l-quad (4 l), cr: 16 c per pass
#pragma unroll
    for (int p = 0; p < 4; ++p) {
      int c = p * 16 + cr;
      f4 v = *(const f4*)(xb + (size_t)c * LL + lq * 4);
#pragma unroll
      for (int j = 0; j < 4; ++j) tile[c][lq * 4 + j] = f2bf(v[j]);
    }
  }
  __syncthreads();
  unsigned short* xo = xT + (size_t)n * LL * CC + (size_t)(lt * 64) * CC + ct * 64;
  {
    const int cq = t & 15, lr = t >> 4;      // cq: c-quad, lr: 16 l per pass
#pragma unroll
    for (int p = 0; p < 4; ++p) {
      int l = p * 16 + lr;
      ushort4 s;
      s.x = tile[cq * 4 + 0][l];
      s.y = tile[cq * 4 + 1][l];
      s.z = tile[cq * 4 + 2][l];
      s.w = tile[cq * 4 + 3][l];
      *(ushort4*)(xo + (size_t)l * CC + cq * 4) = s;
    }
  }
}

// ---- kernel 1 v3: projections, 128(ci) x 128(L) tiles. + setprio around MFMA.
__global__ __launch_bounds__(256, 2) void k_proj(const unsigned short* Wbf,
    const float* bth, const float* bph, const float* bg,
    const unsigned short* xT, unsigned short* QT, unsigned short* KT, unsigned short* Vb) {
  __shared__ unsigned short wtile[2][8192];   // 128 ci x 64 k
  __shared__ unsigned short xtile[2][8192];   // 128 L  x 64 k
  const int bid = blockIdx.x;
  const int n = bid & 7, t = bid >> 3;
  const int lt = t % 25, z = t / 25;          // lt: 25 tiles of 128 L (3200, tail masked)
  const int proj = z >> 1, cith = z & 1;
  const int tid = threadIdx.x;
  const int wave = tid >> 6, lane = tid & 63;
  const int quad = lane >> 4, c16 = lane & 15;

  const unsigned short* Wg = Wbf + proj * 131072 + (size_t)(cith * 128) * CC;
  const unsigned short* Xg = xT + (size_t)n * LL * CC + (size_t)(lt * 128) * CC;

  auto issue = [&](int chunk, int b) {
    const int cb = chunk * 64;
#pragma unroll
    for (int i = 0; i < 4; ++i) {
      int seg = i * 4 + wave;
      int p = seg * 64 + lane;
      int r = p >> 3, sl = p & 7, g = sl ^ (r & 7);
      gload_lds16(Wg + (size_t)r * CC + cb + g * 8, &wtile[b][seg * 512]);
    }
#pragma unroll
    for (int i = 0; i < 4; ++i) {
      int seg = i * 4 + wave;
      int p = seg * 64 + lane;
      int r = p >> 3, sl = p & 7, g = sl ^ (r & 7);
      gload_lds16(Xg + (size_t)r * CC + cb + g * 8, &xtile[b][seg * 512]);
    }
  };

  const f4 zz = {0.f, 0.f, 0.f, 0.f};
  f4 acc[2][8];
#pragma unroll
  for (int i = 0; i < 2; ++i)
#pragma unroll
    for (int j = 0; j < 8; ++j) acc[i][j] = zz;

  issue(0, 0);
  for (int chunk = 0; chunk < 8; ++chunk) {
    __syncthreads();
    if (chunk + 1 < 8) issue(chunk + 1, (chunk + 1) & 1);
    const int bb = chunk & 1;
    __builtin_amdgcn_s_setprio(1);
#pragma unroll
    for (int kc = 0; kc < 2; ++kc) {
      const int slot = (kc * 4 + quad) ^ (c16 & 7);
      bf8 wf[2], xf[8];
#pragma unroll
      for (int sub = 0; sub < 2; ++sub)
        wf[sub] = *(const bf8*)(&wtile[bb][(wave * 32 + sub * 16 + c16) * 64 + slot * 8]);
#pragma unroll
      for (int nt = 0; nt < 8; ++nt)
        xf[nt] = *(const bf8*)(&xtile[bb][(nt * 16 + c16) * 64 + slot * 8]);
      if (proj < 2) {
#pragma unroll
        for (int sub = 0; sub < 2; ++sub)
#pragma unroll
          for (int nt = 0; nt < 8; ++nt)
            acc[sub][nt] = mfma_bf16(wf[sub], xf[nt], acc[sub][nt]);
      } else {
#pragma unroll
        for (int sub = 0; sub < 2; ++sub)
#pragma unroll
          for (int nt = 0; nt < 8; ++nt)
            acc[sub][nt] = mfma_bf16(xf[nt], wf[sub], acc[sub][nt]);
      }
    }
    __builtin_amdgcn_s_setprio(0);
  }

  if (proj < 2) {
    const float* bias = proj == 0 ? bth : bph;
    unsigned short* dst = proj == 0 ? QT : KT;
#pragma unroll
    for (int sub = 0; sub < 2; ++sub) {
      const int ciB = cith * 128 + wave * 32 + sub * 16 + quad * 4;
      const float b0 = bias[ciB + 0], b1 = bias[ciB + 1];
      const float b2 = bias[ciB + 2], b3 = bias[ciB + 3];
#pragma unroll
      for (int nt = 0; nt < 8; ++nt) {
        int l = lt * 128 + nt * 16 + c16;
        if (l < LL) {
          ushort4 v;
          v.x = f2bf(acc[sub][nt][0] + b0);
          v.y = f2bf(acc[sub][nt][1] + b1);
          v.z = f2bf(acc[sub][nt][2] + b2);
          v.w = f2bf(acc[sub][nt][3] + b3);
          *(ushort4*)(dst + ((size_t)n * LL + l) * CIN + ciB) = v;
        }
      }
    }
  } else {
#pragma unroll
    for (int sub = 0; sub < 2; ++sub) {
      const int ci = cith * 128 + wave * 32 + sub * 16 + c16;
      const float bv = bg[ci];
#pragma unroll
      for (int nt = 0; nt < 8; ++nt) {
        int l = lt * 128 + nt * 16 + quad * 4;
        if (l < LL) {
          ushort4 v;
          v.x = f2bf(acc[sub][nt][0] + bv);
          v.y = f2bf(acc[sub][nt][1] + bv);
          v.z = f2bf(acc[sub][nt][2] + bv);
          v.w = f2bf(acc[sub][nt][3] + bv);
          *(ushort4*)(Vb + ((size_t)n * CIN + ci) * LL + l) = v;
        }
      }
    }
  }
}

// ---- kernel 2 v9: flash attention (unchanged): swapped QK^T, in-register
// softmax (T12), s_setprio around MFMA clusters (T5).
__global__ __launch_bounds__(256, 2) void k_attn(const unsigned short* QT, const unsigned short* KT,
                                                 const unsigned short* Vb, unsigned short* Opart,
                                                 float* denp) {
  __shared__ unsigned short kbuf[2][8192];   // 32 keys x 256 shorts, granule slot = g ^ row
  __shared__ unsigned short vbuf[2][8192];   // 256 ci x 32 shorts, slot = g ^ ((row>>1)&3)
  const int bid = blockIdx.x;
  const int n = bid & 7, ks = (bid >> 3) & 1, qb = bid >> 4;
  const int tid = threadIdx.x;
  const int wave = tid >> 6, lane = tid & 63;
  const int l31 = lane & 31, half = lane >> 5;
  int q0 = qb * 128 + wave * 32;
  const bool do_store = q0 < LL;
  if (q0 > LL - 32) q0 = LL - 32;      // tail: waves 2,3 duplicate wave-1 rows, stores masked
  const unsigned short* Qb = QT + ((size_t)n * LL + q0) * CIN;
  const unsigned short* Kks = KT + (size_t)n * LL * CIN + (size_t)(ks * 49 * 32) * CIN;
  const unsigned short* Vks = Vb + (size_t)n * CIN * LL + ks * 49 * 32;

  // Q fragments (m=l31, k=kc*16+half*8+j), softmax scale folded.
  const float qs = 0.09016844005556021f;   // log2(e)/16
  bf8 qf[16];
#pragma unroll
  for (int kc = 0; kc < 16; ++kc) {
    bf8 q = *(const bf8*)(Qb + (size_t)l31 * CIN + kc * 16 + half * 8);
#pragma unroll
    for (int e = 0; e < 8; ++e) {
      float f = __uint_as_float(((unsigned)(unsigned short)q[e]) << 16) * qs;
      q[e] = (short)f2bf(f);
    }
    qf[kc] = q;
  }

  f16v o[8];
#pragma unroll
  for (int t = 0; t < 8; ++t)
#pragma unroll
    for (int r = 0; r < 16; ++r) o[t][r] = 0.f;
  float sden = 0.f;   // per-lane partial denominator for q-row l31 (this lane's key set)

  auto issue = [&](int kt, int b) {
    const int k0 = kt * 32;
    const unsigned short* Kg = Kks + (size_t)k0 * CIN;
    const unsigned short* Vg = Vks + k0;
#pragma unroll
    for (int i = 0; i < 4; ++i) {
      int seg = i * 4 + wave;
      int idx = seg * 64 + lane;
      {
        int r = idx >> 5, sl = idx & 31, g = sl ^ r;
        gload_lds16(Kg + r * CIN + g * 8, &kbuf[b][seg * 512]);
      }
      {
        int r = idx >> 2, sl = idx & 3, g = sl ^ ((r >> 1) & 3);
        gload_lds16(Vg + (size_t)r * LL + g * 8, &vbuf[b][seg * 512]);
      }
    }
  };

  issue(0, 0);
  for (int kt = 0; kt < 49; ++kt) {
    __syncthreads();                   // tile kt resident; prev compute done
    if (kt + 1 < 49) issue(kt + 1, (kt + 1) & 1);
    const int b = kt & 1;
    const unsigned short* kb = &kbuf[b][0];
    const unsigned short* vbp = &vbuf[b][0];

    // S^T = K Q^T : A-frag key row = l31 (granule g = kc*2+half, slot = g ^ l31),
    // B-frag = qf. C layout: col = q = l31, row = key kr(r,half)=(r&3)+8*(r>>2)+4*half.
    f16v sc;
#pragma unroll
    for (int r = 0; r < 16; ++r) sc[r] = 0.f;
    __builtin_amdgcn_s_setprio(1);
#pragma unroll
    for (int kc = 0; kc < 16; ++kc) {
      int slot = (kc * 2 + half) ^ l31;
      bf8 kf = *(const bf8*)(kb + l31 * 256 + slot * 8);
      sc = mfma32(kf, qf[kc], sc);
    }
    __builtin_amdgcn_s_setprio(0);

    // Per 16-key chunk m: exp2 -> denominator tree -> cvtpk/permlane -> af[m].
    bf8 af[2];
#pragma unroll
    for (int m = 0; m < 2; ++m) {
      float p0 = __builtin_amdgcn_exp2f(sc[8 * m + 0]);
      float p1 = __builtin_amdgcn_exp2f(sc[8 * m + 1]);
      float p2 = __builtin_amdgcn_exp2f(sc[8 * m + 2]);
      float p3 = __builtin_amdgcn_exp2f(sc[8 * m + 3]);
      float p4 = __builtin_amdgcn_exp2f(sc[8 * m + 4]);
      float p5 = __builtin_amdgcn_exp2f(sc[8 * m + 5]);
      float p6 = __builtin_amdgcn_exp2f(sc[8 * m + 6]);
      float p7 = __builtin_amdgcn_exp2f(sc[8 * m + 7]);
      sden += ((p0 + p1) + (p2 + p3)) + ((p4 + p5) + (p6 + p7));
      int x0 = cvtpk_bf16(p0, p1);
      int y0 = cvtpk_bf16(p4, p5);
      int x1 = cvtpk_bf16(p2, p3);
      int y1 = cvtpk_bf16(p6, p7);
      asm("v_permlane32_swap_b32 %0, %1" : "+v"(x0), "+v"(y0));
      asm("v_permlane32_swap_b32 %0, %1" : "+v"(x1), "+v"(y1));
      i4 w;
      w[0] = x0; w[1] = x1; w[2] = y0; w[3] = y1;
      af[m] = *(bf8*)&w;
    }

    // O += P V : V row = t*32+l31 (ci), granule g = kc2*2+half, slot = g ^ ((l31>>1)&3)
    __builtin_amdgcn_s_setprio(1);
#pragma unroll
    for (int t = 0; t < 8; ++t) {
#pragma unroll
      for (int kc2 = 0; kc2 < 2; ++kc2) {
        int slot = (kc2 * 2 + half) ^ ((l31 >> 1) & 3);
        bf8 v = *(const bf8*)(vbp + (t * 32 + l31) * 32 + slot * 8);
        o[t] = mfma32(af[kc2], v, o[t]);
      }
    }
    __builtin_amdgcn_s_setprio(0);
  }

  // combine the two key-half partial denominators; lane l31 (both halves) holds den[row l31]
  sden += __shfl_xor(sden, 32);

  if (do_store) {
    if (lane < 32) denp[((size_t)ks * NB + n) * LL + q0 + l31] = sden;
    unsigned short* Ob = Opart + (((size_t)ks * NB + n) * LL + q0) * CIN;
#pragma unroll
    for (int t = 0; t < 8; ++t)
#pragma unroll
      for (int r = 0; r < 16; ++r) {
        int row = (r & 3) + 8 * (r >> 2) + 4 * half;
        Ob[(size_t)row * CIN + t * 32 + l31] = f2bf(o[t][r]);
      }
  }
}

// ---- kernel 3 v5: out = x + b_out + Wout @ ((O0+O1)/den), 128(c) x 128(L) tiles.
// k_den fused: invden computed per-block into LDS before the first barrier.
__global__ __launch_bounds__(256, 2) void k_out(const unsigned short* O0, const unsigned short* O1,
    const unsigned short* Wo, const float* bout, const float* denp,
    const float* x, float* out) {
  __shared__ unsigned short wtile[2][8192];   // 128 c x 64 kci
  __shared__ unsigned short otile[2][8192];   // 128 L x 64 kci
  __shared__ float ivbuf[128];
  const int bid = blockIdx.x;
  const int n = bid & 7, t = bid >> 3;
  const int lt = t % 25, cth = t / 25;        // lt: 25 tiles of 128 L; cth < 4
  const int tid = threadIdx.x;
  const int wave = tid >> 6, lane = tid & 63;
  const int quad = lane >> 4, c16 = lane & 15;

  const unsigned short* Wg = Wo + (size_t)(cth * 128) * CIN;
  const unsigned short* Og0 = O0 + ((size_t)n * LL + lt * 128) * CIN;
  const unsigned short* Og1 = O1 + ((size_t)n * LL + lt * 128) * CIN;

  auto issue = [&](int chunk, int b) {
    const int cb = (chunk & 3) * 64;
    const unsigned short* Og = chunk < 4 ? Og0 : Og1;
#pragma unroll
    for (int i = 0; i < 4; ++i) {
      int seg = i * 4 + wave;
      int p = seg * 64 + lane;
      int r = p >> 3, sl = p & 7, g = sl ^ (r & 7);
      gload_lds16(Wg + (size_t)r * CIN + cb + g * 8, &wtile[b][seg * 512]);
    }
#pragma unroll
    for (int i = 0; i < 4; ++i) {
      int seg = i * 4 + wave;
      int p = seg * 64 + lane;
      int r = p >> 3, sl = p & 7, g = sl ^ (r & 7);
      gload_lds16(Og + (size_t)r * CIN + cb + g * 8, &otile[b][seg * 512]);
    }
  };

  const f4 zz = {0.f, 0.f, 0.f, 0.f};
  f4 acc[8][2];
#pragma unroll
  for (int i = 0; i < 8; ++i)
#pragma unroll
    for (int j = 0; j < 2; ++j) acc[i][j] = zz;

  issue(0, 0);
  // fused k_den: invden for this block's 128 L-rows (before first barrier)
  if (tid < 128) {
    int l = lt * 128 + tid;
    float d = 1.f;
    if (l < LL) d = 1.f / (denp[(size_t)n * LL + l] + denp[(size_t)(NB + n) * LL + l]);
    ivbuf[tid] = d;
  }
  for (int chunk = 0; chunk < 8; ++chunk) {
    __syncthreads();
    if (chunk + 1 < 8) issue(chunk + 1, (chunk + 1) & 1);
    const int bb = chunk & 1;
    __builtin_amdgcn_s_setprio(1);
#pragma unroll
    for (int kc = 0; kc < 2; ++kc) {
      const int slot = (kc * 4 + quad) ^ (c16 & 7);
      bf8 wf[2], ofr[8];
#pragma unroll
      for (int sub = 0; sub < 2; ++sub)
        wf[sub] = *(const bf8*)(&wtile[bb][(wave * 32 + sub * 16 + c16) * 64 + slot * 8]);
#pragma unroll
      for (int nt = 0; nt < 8; ++nt)
        ofr[nt] = *(const bf8*)(&otile[bb][(nt * 16 + c16) * 64 + slot * 8]);
#pragma unroll
      for (int nt = 0; nt < 8; ++nt)
#pragma unroll
        for (int sub = 0; sub < 2; ++sub)
          acc[nt][sub] = mfma_bf16(ofr[nt], wf[sub], acc[nt][sub]);
    }
    __builtin_amdgcn_s_setprio(0);
  }

#pragma unroll
  for (int sub = 0; sub < 2; ++sub) {
    const int c = cth * 128 + wave * 32 + sub * 16 + c16;
    const float bv = bout[c];
#pragma unroll
    for (int nt = 0; nt < 8; ++nt) {
      int l = lt * 128 + nt * 16 + quad * 4;
      if (l < LL) {
        f4 iv = *(const f4*)&ivbuf[nt * 16 + quad * 4];
        size_t base = ((size_t)n * CC + c) * LL + l;
        f4 xv = *(const f4*)(x + base);
        f4 r;
        r[0] = xv[0] + bv + acc[nt][sub][0] * iv[0];
        r[1] = xv[1] + bv + acc[nt][sub][1] * iv[1];
        r[2] = xv[2] + bv + acc[nt][sub][2] * iv[2];
        r[3] = xv[3] + bv + acc[nt][sub][3] * iv[3];
        *(f4*)(out + base) = r;
      }
    }
  }
}

extern "C" void kernel_launch(void* const* d_in, const int* in_sizes, int n_in,
                              void* d_out, int out_size, void* d_ws, size_t ws_size,
                              hipStream_t stream) {
  const float* x     = (const float*)d_in[0];
  const float* W_g   = (const float*)d_in[1];
  const float* b_g   = (const float*)d_in[2];
  const float* W_th  = (const float*)d_in[3];
  const float* b_th  = (const float*)d_in[4];
  const float* W_ph  = (const float*)d_in[5];
  const float* b_ph  = (const float*)d_in[6];
  const float* W_out = (const float*)d_in[7];
  const float* b_out = (const float*)d_in[8];

  char* ws = (char*)d_ws;
  const size_t SZ_W  = 1048576;            // 4 x 131072 bf16
  const size_t SZ_P  = 12845056;           // 8*3136*256*2 bytes
  unsigned short* Wbf = (unsigned short*)(ws);
  unsigned short* QT  = (unsigned short*)(ws + SZ_W);
  unsigned short* KT  = (unsigned short*)(ws + SZ_W + SZ_P);
  unsigned short* Vb  = (unsigned short*)(ws + SZ_W + 2 * SZ_P);
  unsigned short* xT  = (unsigned short*)(ws + SZ_W + 3 * SZ_P);   // 2*SZ_P bytes
  unsigned short* O0  = xT;                 // alias: xT dead after k_proj
  unsigned short* O1  = (unsigned short*)(ws + SZ_W + 4 * SZ_P);
  float* denp   = (float*)(ws + SZ_W + 5 * SZ_P);                  // 2*NB*LL fp32
  float* out = (float*)d_out;

  k_cvt<<<5184, 256, 0, stream>>>(W_th, W_ph, W_g, W_out, Wbf, x, xT);
  k_proj<<<1200, 256, 0, stream>>>(Wbf, b_th, b_ph, b_g, xT, QT, KT, Vb);
  k_attn<<<400, 256, 0, stream>>>(QT, KT, Vb, O0, denp);
  k_out<<<800, 256, 0, stream>>>(O0, O1, Wbf + 3 * 131072, b_out, denp, x, out);
}

// Round 7
// 276.006 us; speedup vs baseline: 1.0525x; 1.0119x over previous
//
#include <hip/hip_runtime.h>
#include <stdint.h>

#define NB 8
#define CC 512
#define LL 3136
#define CIN 256

typedef __attribute__((ext_vector_type(8))) short bf8;
typedef __attribute__((ext_vector_type(4))) float f4;
typedef __attribute__((ext_vector_type(16))) float f16v;
typedef __attribute__((ext_vector_type(4))) int i4;

__device__ __forceinline__ f4 mfma_bf16(bf8 a, bf8 b, f4 c) {
  return __builtin_amdgcn_mfma_f32_16x16x32_bf16(a, b, c, 0, 0, 0);
}

__device__ __forceinline__ f16v mfma32(bf8 a, bf8 b, f16v c) {
  return __builtin_amdgcn_mfma_f32_32x32x16_bf16(a, b, c, 0, 0, 0);
}

__device__ __forceinline__ unsigned short f2bf(float f) {
  unsigned int u = __float_as_uint(f);
  u += 0x7FFFu + ((u >> 16) & 1u);
  return (unsigned short)(u >> 16);
}

// packed f32x2 -> bf16x2 (RNE), low word = lo, high word = hi
__device__ __forceinline__ int cvtpk_bf16(float lo, float hi) {
  int r;
  asm("v_cvt_pk_bf16_f32 %0, %1, %2" : "=v"(r) : "v"(lo), "v"(hi));
  return r;
}

__device__ __forceinline__ void gload_lds16(const unsigned short* g, unsigned short* l) {
  __builtin_amdgcn_global_load_lds(
      (const __attribute__((address_space(1))) void*)g,
      (__attribute__((address_space(3))) void*)l, 16, 0, 0);
}

// ---- kernel 0 (merged): weight bf16 convert + x transpose.
// bid <  3136 : transpose x (n,C,L) fp32 -> xT (n,L,C) bf16, 64x64 tile.
// bid >= 3136 : convert weights. layout: [Wth][Wph][Wg][Wout]
__global__ __launch_bounds__(256) void k_cvt(const float* Wth, const float* Wph, const float* Wg,
                                             const float* Wout, unsigned short* Wbf,
                                             const float* x, unsigned short* xT) {
  const int bid = blockIdx.x;
  const int t = threadIdx.x;
  if (bid >= 3136) {                       // ---- weight convert part
    int i = (bid - 3136) * 256 + t;
    int which = i >> 17, off = i & 131071;
    const float* s = which == 0 ? Wth : which == 1 ? Wph : which == 2 ? Wg : Wout;
    Wbf[i] = f2bf(s[off]);
    return;
  }
  // ---- transpose part
  __shared__ unsigned short tile[64][66];
  const int lt = bid % 49;
  const int rest = bid / 49;
  const int n = rest & 7, ct = rest >> 3;
  const float* xb = x + (size_t)n * CC * LL + (size_t)(ct * 64) * LL + lt * 64;
  {
    const int lq = t & 15, cr = t >> 4;      // lq: l-quad (4 l), cr: 16 c per pass
#pragma unroll
    for (int p = 0; p < 4; ++p) {
      int c = p * 16 + cr;
      f4 v = *(const f4*)(xb + (size_t)c * LL + lq * 4);
#pragma unroll
      for (int j = 0; j < 4; ++j) tile[c][lq * 4 + j] = f2bf(v[j]);
    }
  }
  __syncthreads();
  unsigned short* xo = xT + (size_t)n * LL * CC + (size_t)(lt * 64) * CC + ct * 64;
  {
    const int cq = t & 15, lr = t >> 4;      // cq: c-quad, lr: 16 l per pass
#pragma unroll
    for (int p = 0; p < 4; ++p) {
      int l = p * 16 + lr;
      ushort4 s;
      s.x = tile[cq * 4 + 0][l];
      s.y = tile[cq * 4 + 1][l];
      s.z = tile[cq * 4 + 2][l];
      s.w = tile[cq * 4 + 3][l];
      *(ushort4*)(xo + (size_t)l * CC + cq * 4) = s;
    }
  }
}

// ---- kernel 1 v4: projections, 128(ci) x 160(L) tiles, grid 960 (2 rounds @ 94% slot-eff).
__global__ __launch_bounds__(256, 2) void k_proj(const unsigned short* Wbf,
    const float* bth, const float* bph, const float* bg,
    const unsigned short* xT, unsigned short* QT, unsigned short* KT, unsigned short* Vb) {
  __shared__ unsigned short wtile[2][8192];    // 128 ci x 64 k
  __shared__ unsigned short xtile[2][10240];   // 160 L  x 64 k
  const int bid = blockIdx.x;
  const int n = bid & 7, t = bid >> 3;
  const int lt = t % 20, z = t / 20;           // lt: 20 tiles of 160 L (3200, tail masked)
  const int proj = z >> 1, cith = z & 1;
  const int tid = threadIdx.x;
  const int wave = tid >> 6, lane = tid & 63;
  const int quad = lane >> 4, c16 = lane & 15;

  const unsigned short* Wg = Wbf + proj * 131072 + (size_t)(cith * 128) * CC;
  const unsigned short* Xg = xT + (size_t)n * LL * CC + (size_t)(lt * 160) * CC;

  auto issue = [&](int chunk, int b) {
    const int cb = chunk * 64;
#pragma unroll
    for (int i = 0; i < 4; ++i) {
      int seg = i * 4 + wave;
      int p = seg * 64 + lane;
      int r = p >> 3, sl = p & 7, g = sl ^ (r & 7);
      gload_lds16(Wg + (size_t)r * CC + cb + g * 8, &wtile[b][seg * 512]);
    }
#pragma unroll
    for (int i = 0; i < 5; ++i) {              // 20 segs: 160 rows x 64 shorts
      int seg = i * 4 + wave;
      int p = seg * 64 + lane;
      int r = p >> 3, sl = p & 7, g = sl ^ (r & 7);
      gload_lds16(Xg + (size_t)r * CC + cb + g * 8, &xtile[b][seg * 512]);
    }
  };

  const f4 zz = {0.f, 0.f, 0.f, 0.f};
  f4 acc[2][10];
#pragma unroll
  for (int i = 0; i < 2; ++i)
#pragma unroll
    for (int j = 0; j < 10; ++j) acc[i][j] = zz;

  issue(0, 0);
  for (int chunk = 0; chunk < 8; ++chunk) {
    __syncthreads();
    if (chunk + 1 < 8) issue(chunk + 1, (chunk + 1) & 1);
    const int bb = chunk & 1;
    __builtin_amdgcn_s_setprio(1);
#pragma unroll
    for (int kc = 0; kc < 2; ++kc) {
      const int slot = (kc * 4 + quad) ^ (c16 & 7);
      bf8 wf[2], xf[10];
#pragma unroll
      for (int sub = 0; sub < 2; ++sub)
        wf[sub] = *(const bf8*)(&wtile[bb][(wave * 32 + sub * 16 + c16) * 64 + slot * 8]);
#pragma unroll
      for (int nt = 0; nt < 10; ++nt)
        xf[nt] = *(const bf8*)(&xtile[bb][(nt * 16 + c16) * 64 + slot * 8]);
      if (proj < 2) {
#pragma unroll
        for (int sub = 0; sub < 2; ++sub)
#pragma unroll
          for (int nt = 0; nt < 10; ++nt)
            acc[sub][nt] = mfma_bf16(wf[sub], xf[nt], acc[sub][nt]);
      } else {
#pragma unroll
        for (int sub = 0; sub < 2; ++sub)
#pragma unroll
          for (int nt = 0; nt < 10; ++nt)
            acc[sub][nt] = mfma_bf16(xf[nt], wf[sub], acc[sub][nt]);
      }
    }
    __builtin_amdgcn_s_setprio(0);
  }

  if (proj < 2) {
    const float* bias = proj == 0 ? bth : bph;
    unsigned short* dst = proj == 0 ? QT : KT;
#pragma unroll
    for (int sub = 0; sub < 2; ++sub) {
      const int ciB = cith * 128 + wave * 32 + sub * 16 + quad * 4;
      const float b0 = bias[ciB + 0], b1 = bias[ciB + 1];
      const float b2 = bias[ciB + 2], b3 = bias[ciB + 3];
#pragma unroll
      for (int nt = 0; nt < 10; ++nt) {
        int l = lt * 160 + nt * 16 + c16;
        if (l < LL) {
          ushort4 v;
          v.x = f2bf(acc[sub][nt][0] + b0);
          v.y = f2bf(acc[sub][nt][1] + b1);
          v.z = f2bf(acc[sub][nt][2] + b2);
          v.w = f2bf(acc[sub][nt][3] + b3);
          *(ushort4*)(dst + ((size_t)n * LL + l) * CIN + ciB) = v;
        }
      }
    }
  } else {
#pragma unroll
    for (int sub = 0; sub < 2; ++sub) {
      const int ci = cith * 128 + wave * 32 + sub * 16 + c16;
      const float bv = bg[ci];
#pragma unroll
      for (int nt = 0; nt < 10; ++nt) {
        int l = lt * 160 + nt * 16 + quad * 4;
        if (l < LL) {
          ushort4 v;
          v.x = f2bf(acc[sub][nt][0] + bv);
          v.y = f2bf(acc[sub][nt][1] + bv);
          v.z = f2bf(acc[sub][nt][2] + bv);
          v.w = f2bf(acc[sub][nt][3] + bv);
          *(ushort4*)(Vb + ((size_t)n * CIN + ci) * LL + l) = v;
        }
      }
    }
  }
}

// ---- kernel 2 v9: flash attention (unchanged): swapped QK^T, in-register
// softmax (T12), s_setprio around MFMA clusters (T5).
__global__ __launch_bounds__(256, 2) void k_attn(const unsigned short* QT, const unsigned short* KT,
                                                 const unsigned short* Vb, unsigned short* Opart,
                                                 float* denp) {
  __shared__ unsigned short kbuf[2][8192];   // 32 keys x 256 shorts, granule slot = g ^ row
  __shared__ unsigned short vbuf[2][8192];   // 256 ci x 32 shorts, slot = g ^ ((row>>1)&3)
  const int bid = blockIdx.x;
  const int n = bid & 7, ks = (bid >> 3) & 1, qb = bid >> 4;
  const int tid = threadIdx.x;
  const int wave = tid >> 6, lane = tid & 63;
  const int l31 = lane & 31, half = lane >> 5;
  int q0 = qb * 128 + wave * 32;
  const bool do_store = q0 < LL;
  if (q0 > LL - 32) q0 = LL - 32;      // tail: waves 2,3 duplicate wave-1 rows, stores masked
  const unsigned short* Qb = QT + ((size_t)n * LL + q0) * CIN;
  const unsigned short* Kks = KT + (size_t)n * LL * CIN + (size_t)(ks * 49 * 32) * CIN;
  const unsigned short* Vks = Vb + (size_t)n * CIN * LL + ks * 49 * 32;

  // Q fragments (m=l31, k=kc*16+half*8+j), softmax scale folded.
  const float qs = 0.09016844005556021f;   // log2(e)/16
  bf8 qf[16];
#pragma unroll
  for (int kc = 0; kc < 16; ++kc) {
    bf8 q = *(const bf8*)(Qb + (size_t)l31 * CIN + kc * 16 + half * 8);
#pragma unroll
    for (int e = 0; e < 8; ++e) {
      float f = __uint_as_float(((unsigned)(unsigned short)q[e]) << 16) * qs;
      q[e] = (short)f2bf(f);
    }
    qf[kc] = q;
  }

  f16v o[8];
#pragma unroll
  for (int t = 0; t < 8; ++t)
#pragma unroll
    for (int r = 0; r < 16; ++r) o[t][r] = 0.f;
  float sden = 0.f;   // per-lane partial denominator for q-row l31 (this lane's key set)

  auto issue = [&](int kt, int b) {
    const int k0 = kt * 32;
    const unsigned short* Kg = Kks + (size_t)k0 * CIN;
    const unsigned short* Vg = Vks + k0;
#pragma unroll
    for (int i = 0; i < 4; ++i) {
      int seg = i * 4 + wave;
      int idx = seg * 64 + lane;
      {
        int r = idx >> 5, sl = idx & 31, g = sl ^ r;
        gload_lds16(Kg + r * CIN + g * 8, &kbuf[b][seg * 512]);
      }
      {
        int r = idx >> 2, sl = idx & 3, g = sl ^ ((r >> 1) & 3);
        gload_lds16(Vg + (size_t)r * LL + g * 8, &vbuf[b][seg * 512]);
      }
    }
  };

  issue(0, 0);
  for (int kt = 0; kt < 49; ++kt) {
    __syncthreads();                   // tile kt resident; prev compute done
    if (kt + 1 < 49) issue(kt + 1, (kt + 1) & 1);
    const int b = kt & 1;
    const unsigned short* kb = &kbuf[b][0];
    const unsigned short* vbp = &vbuf[b][0];

    // S^T = K Q^T : A-frag key row = l31 (granule g = kc*2+half, slot = g ^ l31),
    // B-frag = qf. C layout: col = q = l31, row = key kr(r,half)=(r&3)+8*(r>>2)+4*half.
    f16v sc;
#pragma unroll
    for (int r = 0; r < 16; ++r) sc[r] = 0.f;
    __builtin_amdgcn_s_setprio(1);
#pragma unroll
    for (int kc = 0; kc < 16; ++kc) {
      int slot = (kc * 2 + half) ^ l31;
      bf8 kf = *(const bf8*)(kb + l31 * 256 + slot * 8);
      sc = mfma32(kf, qf[kc], sc);
    }
    __builtin_amdgcn_s_setprio(0);

    // Per 16-key chunk m: exp2 -> denominator tree -> cvtpk/permlane -> af[m].
    bf8 af[2];
#pragma unroll
    for (int m = 0; m < 2; ++m) {
      float p0 = __builtin_amdgcn_exp2f(sc[8 * m + 0]);
      float p1 = __builtin_amdgcn_exp2f(sc[8 * m + 1]);
      float p2 = __builtin_amdgcn_exp2f(sc[8 * m + 2]);
      float p3 = __builtin_amdgcn_exp2f(sc[8 * m + 3]);
      float p4 = __builtin_amdgcn_exp2f(sc[8 * m + 4]);
      float p5 = __builtin_amdgcn_exp2f(sc[8 * m + 5]);
      float p6 = __builtin_amdgcn_exp2f(sc[8 * m + 6]);
      float p7 = __builtin_amdgcn_exp2f(sc[8 * m + 7]);
      sden += ((p0 + p1) + (p2 + p3)) + ((p4 + p5) + (p6 + p7));
      int x0 = cvtpk_bf16(p0, p1);
      int y0 = cvtpk_bf16(p4, p5);
      int x1 = cvtpk_bf16(p2, p3);
      int y1 = cvtpk_bf16(p6, p7);
      asm("v_permlane32_swap_b32 %0, %1" : "+v"(x0), "+v"(y0));
      asm("v_permlane32_swap_b32 %0, %1" : "+v"(x1), "+v"(y1));
      i4 w;
      w[0] = x0; w[1] = x1; w[2] = y0; w[3] = y1;
      af[m] = *(bf8*)&w;
    }

    // O += P V : V row = t*32+l31 (ci), granule g = kc2*2+half, slot = g ^ ((l31>>1)&3)
    __builtin_amdgcn_s_setprio(1);
#pragma unroll
    for (int t = 0; t < 8; ++t) {
#pragma unroll
      for (int kc2 = 0; kc2 < 2; ++kc2) {
        int slot = (kc2 * 2 + half) ^ ((l31 >> 1) & 3);
        bf8 v = *(const bf8*)(vbp + (t * 32 + l31) * 32 + slot * 8);
        o[t] = mfma32(af[kc2], v, o[t]);
      }
    }
    __builtin_amdgcn_s_setprio(0);
  }

  // combine the two key-half partial denominators; lane l31 (both halves) holds den[row l31]
  sden += __shfl_xor(sden, 32);

  if (do_store) {
    if (lane < 32) denp[((size_t)ks * NB + n) * LL + q0 + l31] = sden;
    unsigned short* Ob = Opart + (((size_t)ks * NB + n) * LL + q0) * CIN;
#pragma unroll
    for (int t = 0; t < 8; ++t)
#pragma unroll
      for (int r = 0; r < 16; ++r) {
        int row = (r & 3) + 8 * (r >> 2) + 4 * half;
        Ob[(size_t)row * CIN + t * 32 + l31] = f2bf(o[t][r]);
      }
  }
}

// ---- kernel 3 v6: out = x + b_out + Wout @ ((O0+O1)/den), 128(c) x 112(L) tiles.
// 3136 = 112*28 exactly: no tail, no guards, no OOB staging reads. Grid 896 (2 rounds).
__global__ __launch_bounds__(256, 2) void k_out(const unsigned short* O0, const unsigned short* O1,
    const unsigned short* Wo, const float* bout, const float* denp,
    const float* x, float* out) {
  __shared__ unsigned short wtile[2][8192];   // 128 c x 64 kci
  __shared__ unsigned short otile[2][7168];   // 112 L x 64 kci
  __shared__ float ivbuf[112];
  const int bid = blockIdx.x;
  const int n = bid & 7, t = bid >> 3;
  const int lt = t % 28, cth = t / 28;        // lt: 28 tiles of 112 L (exact); cth < 4
  const int tid = threadIdx.x;
  const int wave = tid >> 6, lane = tid & 63;
  const int quad = lane >> 4, c16 = lane & 15;

  const unsigned short* Wg = Wo + (size_t)(cth * 128) * CIN;
  const unsigned short* Og0 = O0 + ((size_t)n * LL + lt * 112) * CIN;
  const unsigned short* Og1 = O1 + ((size_t)n * LL + lt * 112) * CIN;

  auto issue = [&](int chunk, int b) {
    const int cb = (chunk & 3) * 64;
    const unsigned short* Og = chunk < 4 ? Og0 : Og1;
#pragma unroll
    for (int i = 0; i < 4; ++i) {
      int seg = i * 4 + wave;
      int p = seg * 64 + lane;
      int r = p >> 3, sl = p & 7, g = sl ^ (r & 7);
      gload_lds16(Wg + (size_t)r * CIN + cb + g * 8, &wtile[b][seg * 512]);
    }
#pragma unroll
    for (int i = 0; i < 4; ++i) {              // 14 segs: 112 rows x 64 shorts
      int seg = i * 4 + wave;
      if (seg < 14) {
        int p = seg * 64 + lane;
        int r = p >> 3, sl = p & 7, g = sl ^ (r & 7);
        gload_lds16(Og + (size_t)r * CIN + cb + g * 8, &otile[b][seg * 512]);
      }
    }
  };

  const f4 zz = {0.f, 0.f, 0.f, 0.f};
  f4 acc[7][2];
#pragma unroll
  for (int i = 0; i < 7; ++i)
#pragma unroll
    for (int j = 0; j < 2; ++j) acc[i][j] = zz;

  issue(0, 0);
  // fused k_den: invden for this block's 112 L-rows (before first barrier)
  if (tid < 112) {
    int l = lt * 112 + tid;   // always < LL (exact tiling)
    ivbuf[tid] = 1.f / (denp[(size_t)n * LL + l] + denp[(size_t)(NB + n) * LL + l]);
  }
  for (int chunk = 0; chunk < 8; ++chunk) {
    __syncthreads();
    if (chunk + 1 < 8) issue(chunk + 1, (chunk + 1) & 1);
    const int bb = chunk & 1;
    __builtin_amdgcn_s_setprio(1);
#pragma unroll
    for (int kc = 0; kc < 2; ++kc) {
      const int slot = (kc * 4 + quad) ^ (c16 & 7);
      bf8 wf[2], ofr[7];
#pragma unroll
      for (int sub = 0; sub < 2; ++sub)
        wf[sub] = *(const bf8*)(&wtile[bb][(wave * 32 + sub * 16 + c16) * 64 + slot * 8]);
#pragma unroll
      for (int nt = 0; nt < 7; ++nt)
        ofr[nt] = *(const bf8*)(&otile[bb][(nt * 16 + c16) * 64 + slot * 8]);
#pragma unroll
      for (int nt = 0; nt < 7; ++nt)
#pragma unroll
        for (int sub = 0; sub < 2; ++sub)
          acc[nt][sub] = mfma_bf16(ofr[nt], wf[sub], acc[nt][sub]);
    }
    __builtin_amdgcn_s_setprio(0);
  }

#pragma unroll
  for (int sub = 0; sub < 2; ++sub) {
    const int c = cth * 128 + wave * 32 + sub * 16 + c16;
    const float bv = bout[c];
#pragma unroll
    for (int nt = 0; nt < 7; ++nt) {
      int l = lt * 112 + nt * 16 + quad * 4;   // always < LL (exact tiling)
      f4 iv = *(const f4*)&ivbuf[nt * 16 + quad * 4];
      size_t base = ((size_t)n * CC + c) * LL + l;
      f4 xv = *(const f4*)(x + base);
      f4 r;
      r[0] = xv[0] + bv + acc[nt][sub][0] * iv[0];
      r[1] = xv[1] + bv + acc[nt][sub][1] * iv[1];
      r[2] = xv[2] + bv + acc[nt][sub][2] * iv[2];
      r[3] = xv[3] + bv + acc[nt][sub][3] * iv[3];
      *(f4*)(out + base) = r;
    }
  }
}

extern "C" void kernel_launch(void* const* d_in, const int* in_sizes, int n_in,
                              void* d_out, int out_size, void* d_ws, size_t ws_size,
                              hipStream_t stream) {
  const float* x     = (const float*)d_in[0];
  const float* W_g   = (const float*)d_in[1];
  const float* b_g   = (const float*)d_in[2];
  const float* W_th  = (const float*)d_in[3];
  const float* b_th  = (const float*)d_in[4];
  const float* W_ph  = (const float*)d_in[5];
  const float* b_ph  = (const float*)d_in[6];
  const float* W_out = (const float*)d_in[7];
  const float* b_out = (const float*)d_in[8];

  char* ws = (char*)d_ws;
  const size_t SZ_W  = 1048576;            // 4 x 131072 bf16
  const size_t SZ_P  = 12845056;           // 8*3136*256*2 bytes
  unsigned short* Wbf = (unsigned short*)(ws);
  unsigned short* QT  = (unsigned short*)(ws + SZ_W);
  unsigned short* KT  = (unsigned short*)(ws + SZ_W + SZ_P);
  unsigned short* Vb  = (unsigned short*)(ws + SZ_W + 2 * SZ_P);
  unsigned short* xT  = (unsigned short*)(ws + SZ_W + 3 * SZ_P);   // 2*SZ_P bytes
  unsigned short* O0  = xT;                 // alias: xT dead after k_proj
  unsigned short* O1  = (unsigned short*)(ws + SZ_W + 4 * SZ_P);
  float* denp   = (float*)(ws + SZ_W + 5 * SZ_P);                  // 2*NB*LL fp32
  float* out = (float*)d_out;

  k_cvt<<<5184, 256, 0, stream>>>(W_th, W_ph, W_g, W_out, Wbf, x, xT);
  k_proj<<<960, 256, 0, stream>>>(Wbf, b_th, b_ph, b_g, xT, QT, KT, Vb);
  k_attn<<<400, 256, 0, stream>>>(QT, KT, Vb, O0, denp);
  k_out<<<896, 256, 0, stream>>>(O0, O1, Wbf + 3 * 131072, b_out, denp, x, out);
}

// Round 8
// 272.584 us; speedup vs baseline: 1.0657x; 1.0126x over previous
//
#include <hip/hip_runtime.h>
#include <stdint.h>

#define NB 8
#define CC 512
#define LL 3136
#define CIN 256

typedef __attribute__((ext_vector_type(8))) short bf8;
typedef __attribute__((ext_vector_type(4))) float f4;
typedef __attribute__((ext_vector_type(16))) float f16v;
typedef __attribute__((ext_vector_type(4))) int i4;

__device__ __forceinline__ f4 mfma_bf16(bf8 a, bf8 b, f4 c) {
  return __builtin_amdgcn_mfma_f32_16x16x32_bf16(a, b, c, 0, 0, 0);
}

__device__ __forceinline__ f16v mfma32(bf8 a, bf8 b, f16v c) {
  return __builtin_amdgcn_mfma_f32_32x32x16_bf16(a, b, c, 0, 0, 0);
}

__device__ __forceinline__ unsigned short f2bf(float f) {
  unsigned int u = __float_as_uint(f);
  u += 0x7FFFu + ((u >> 16) & 1u);
  return (unsigned short)(u >> 16);
}

// packed f32x2 -> bf16x2 (RNE), low word = lo, high word = hi
__device__ __forceinline__ int cvtpk_bf16(float lo, float hi) {
  int r;
  asm("v_cvt_pk_bf16_f32 %0, %1, %2" : "=v"(r) : "v"(lo), "v"(hi));
  return r;
}

__device__ __forceinline__ void gload_lds16(const unsigned short* g, unsigned short* l) {
  __builtin_amdgcn_global_load_lds(
      (const __attribute__((address_space(1))) void*)g,
      (__attribute__((address_space(3))) void*)l, 16, 0, 0);
}

// ---- kernel 0 (merged): weight bf16 convert + x transpose.
__global__ __launch_bounds__(256) void k_cvt(const float* Wth, const float* Wph, const float* Wg,
                                             const float* Wout, unsigned short* Wbf,
                                             const float* x, unsigned short* xT) {
  const int bid = blockIdx.x;
  const int t = threadIdx.x;
  if (bid >= 3136) {                       // ---- weight convert part
    int i = (bid - 3136) * 256 + t;
    int which = i >> 17, off = i & 131071;
    const float* s = which == 0 ? Wth : which == 1 ? Wph : which == 2 ? Wg : Wout;
    Wbf[i] = f2bf(s[off]);
    return;
  }
  // ---- transpose part
  __shared__ unsigned short tile[64][66];
  const int lt = bid % 49;
  const int rest = bid / 49;
  const int n = rest & 7, ct = rest >> 3;
  const float* xb = x + (size_t)n * CC * LL + (size_t)(ct * 64) * LL + lt * 64;
  {
    const int lq = t & 15, cr = t >> 4;
#pragma unroll
    for (int p = 0; p < 4; ++p) {
      int c = p * 16 + cr;
      f4 v = *(const f4*)(xb + (size_t)c * LL + lq * 4);
#pragma unroll
      for (int j = 0; j < 4; ++j) tile[c][lq * 4 + j] = f2bf(v[j]);
    }
  }
  __syncthreads();
  unsigned short* xo = xT + (size_t)n * LL * CC + (size_t)(lt * 64) * CC + ct * 64;
  {
    const int cq = t & 15, lr = t >> 4;
#pragma unroll
    for (int p = 0; p < 4; ++p) {
      int l = p * 16 + lr;
      ushort4 s;
      s.x = tile[cq * 4 + 0][l];
      s.y = tile[cq * 4 + 1][l];
      s.z = tile[cq * 4 + 2][l];
      s.w = tile[cq * 4 + 3][l];
      *(ushort4*)(xo + (size_t)l * CC + cq * 4) = s;
    }
  }
}

// ---- kernel 1 v5: projections, 128(ci) x 160(L) tiles, 512 threads (8 waves).
// 2 blocks/CU x 8 waves = 4 waves/SIMD (was 2) -> doubled latency-hiding TLP.
// Per wave: 32ci strip (w>>1) x 80L half (w&1); acc[2][5], 20 MFMA/chunk.
__global__ __launch_bounds__(512, 4) void k_proj(const unsigned short* Wbf,
    const float* bth, const float* bph, const float* bg,
    const unsigned short* xT, unsigned short* QT, unsigned short* KT, unsigned short* Vb) {
  __shared__ unsigned short wtile[2][8192];    // 128 ci x 64 k
  __shared__ unsigned short xtile[2][10240];   // 160 L  x 64 k
  const int bid = blockIdx.x;
  const int n = bid & 7, t = bid >> 3;
  const int lt = t % 20, z = t / 20;           // lt: 20 tiles of 160 L (3200, tail masked)
  const int proj = z >> 1, cith = z & 1;
  const int tid = threadIdx.x;
  const int wave = tid >> 6, lane = tid & 63;
  const int quad = lane >> 4, c16 = lane & 15;
  const int wci = wave >> 1, wl = wave & 1;    // ci strip 0..3, L half 0..1

  const unsigned short* Wg = Wbf + proj * 131072 + (size_t)(cith * 128) * CC;
  const unsigned short* Xg = xT + (size_t)n * LL * CC + (size_t)(lt * 160) * CC;

  auto issue = [&](int chunk, int b) {
    const int cb = chunk * 64;
#pragma unroll
    for (int i = 0; i < 2; ++i) {              // 16 segs: 128 rows x 64 shorts
      int seg = i * 8 + wave;
      int p = seg * 64 + lane;
      int r = p >> 3, sl = p & 7, g = sl ^ (r & 7);
      gload_lds16(Wg + (size_t)r * CC + cb + g * 8, &wtile[b][seg * 512]);
    }
#pragma unroll
    for (int i = 0; i < 3; ++i) {              // 20 segs: 160 rows x 64 shorts
      int seg = i * 8 + wave;
      if (seg < 20) {
        int p = seg * 64 + lane;
        int r = p >> 3, sl = p & 7, g = sl ^ (r & 7);
        gload_lds16(Xg + (size_t)r * CC + cb + g * 8, &xtile[b][seg * 512]);
      }
    }
  };

  const f4 zz = {0.f, 0.f, 0.f, 0.f};
  f4 acc[2][5];
#pragma unroll
  for (int i = 0; i < 2; ++i)
#pragma unroll
    for (int j = 0; j < 5; ++j) acc[i][j] = zz;

  issue(0, 0);
  for (int chunk = 0; chunk < 8; ++chunk) {
    __syncthreads();
    if (chunk + 1 < 8) issue(chunk + 1, (chunk + 1) & 1);
    const int bb = chunk & 1;
    __builtin_amdgcn_s_setprio(1);
#pragma unroll
    for (int kc = 0; kc < 2; ++kc) {
      const int slot = (kc * 4 + quad) ^ (c16 & 7);
      bf8 wf[2], xf[5];
#pragma unroll
      for (int sub = 0; sub < 2; ++sub)
        wf[sub] = *(const bf8*)(&wtile[bb][(wci * 32 + sub * 16 + c16) * 64 + slot * 8]);
#pragma unroll
      for (int nt = 0; nt < 5; ++nt)
        xf[nt] = *(const bf8*)(&xtile[bb][(wl * 80 + nt * 16 + c16) * 64 + slot * 8]);
      if (proj < 2) {
#pragma unroll
        for (int sub = 0; sub < 2; ++sub)
#pragma unroll
          for (int nt = 0; nt < 5; ++nt)
            acc[sub][nt] = mfma_bf16(wf[sub], xf[nt], acc[sub][nt]);
      } else {
#pragma unroll
        for (int sub = 0; sub < 2; ++sub)
#pragma unroll
          for (int nt = 0; nt < 5; ++nt)
            acc[sub][nt] = mfma_bf16(xf[nt], wf[sub], acc[sub][nt]);
      }
    }
    __builtin_amdgcn_s_setprio(0);
  }

  if (proj < 2) {
    const float* bias = proj == 0 ? bth : bph;
    unsigned short* dst = proj == 0 ? QT : KT;
#pragma unroll
    for (int sub = 0; sub < 2; ++sub) {
      const int ciB = cith * 128 + wci * 32 + sub * 16 + quad * 4;
      const float b0 = bias[ciB + 0], b1 = bias[ciB + 1];
      const float b2 = bias[ciB + 2], b3 = bias[ciB + 3];
#pragma unroll
      for (int nt = 0; nt < 5; ++nt) {
        int l = lt * 160 + wl * 80 + nt * 16 + c16;
        if (l < LL) {
          ushort4 v;
          v.x = f2bf(acc[sub][nt][0] + b0);
          v.y = f2bf(acc[sub][nt][1] + b1);
          v.z = f2bf(acc[sub][nt][2] + b2);
          v.w = f2bf(acc[sub][nt][3] + b3);
          *(ushort4*)(dst + ((size_t)n * LL + l) * CIN + ciB) = v;
        }
      }
    }
  } else {
#pragma unroll
    for (int sub = 0; sub < 2; ++sub) {
      const int ci = cith * 128 + wci * 32 + sub * 16 + c16;
      const float bv = bg[ci];
#pragma unroll
      for (int nt = 0; nt < 5; ++nt) {
        int l = lt * 160 + wl * 80 + nt * 16 + quad * 4;
        if (l < LL) {
          ushort4 v;
          v.x = f2bf(acc[sub][nt][0] + bv);
          v.y = f2bf(acc[sub][nt][1] + bv);
          v.z = f2bf(acc[sub][nt][2] + bv);
          v.w = f2bf(acc[sub][nt][3] + bv);
          *(ushort4*)(Vb + ((size_t)n * CIN + ci) * LL + l) = v;
        }
      }
    }
  }
}

// ---- kernel 2 v9: flash attention (unchanged): swapped QK^T, in-register
// softmax (T12), s_setprio around MFMA clusters (T5). Register-walled at 2 waves/SIMD.
__global__ __launch_bounds__(256, 2) void k_attn(const unsigned short* QT, const unsigned short* KT,
                                                 const unsigned short* Vb, unsigned short* Opart,
                                                 float* denp) {
  __shared__ unsigned short kbuf[2][8192];   // 32 keys x 256 shorts, granule slot = g ^ row
  __shared__ unsigned short vbuf[2][8192];   // 256 ci x 32 shorts, slot = g ^ ((row>>1)&3)
  const int bid = blockIdx.x;
  const int n = bid & 7, ks = (bid >> 3) & 1, qb = bid >> 4;
  const int tid = threadIdx.x;
  const int wave = tid >> 6, lane = tid & 63;
  const int l31 = lane & 31, half = lane >> 5;
  int q0 = qb * 128 + wave * 32;
  const bool do_store = q0 < LL;
  if (q0 > LL - 32) q0 = LL - 32;      // tail: waves 2,3 duplicate wave-1 rows, stores masked
  const unsigned short* Qb = QT + ((size_t)n * LL + q0) * CIN;
  const unsigned short* Kks = KT + (size_t)n * LL * CIN + (size_t)(ks * 49 * 32) * CIN;
  const unsigned short* Vks = Vb + (size_t)n * CIN * LL + ks * 49 * 32;

  // Q fragments (m=l31, k=kc*16+half*8+j), softmax scale folded.
  const float qs = 0.09016844005556021f;   // log2(e)/16
  bf8 qf[16];
#pragma unroll
  for (int kc = 0; kc < 16; ++kc) {
    bf8 q = *(const bf8*)(Qb + (size_t)l31 * CIN + kc * 16 + half * 8);
#pragma unroll
    for (int e = 0; e < 8; ++e) {
      float f = __uint_as_float(((unsigned)(unsigned short)q[e]) << 16) * qs;
      q[e] = (short)f2bf(f);
    }
    qf[kc] = q;
  }

  f16v o[8];
#pragma unroll
  for (int t = 0; t < 8; ++t)
#pragma unroll
    for (int r = 0; r < 16; ++r) o[t][r] = 0.f;
  float sden = 0.f;   // per-lane partial denominator for q-row l31 (this lane's key set)

  auto issue = [&](int kt, int b) {
    const int k0 = kt * 32;
    const unsigned short* Kg = Kks + (size_t)k0 * CIN;
    const unsigned short* Vg = Vks + k0;
#pragma unroll
    for (int i = 0; i < 4; ++i) {
      int seg = i * 4 + wave;
      int idx = seg * 64 + lane;
      {
        int r = idx >> 5, sl = idx & 31, g = sl ^ r;
        gload_lds16(Kg + r * CIN + g * 8, &kbuf[b][seg * 512]);
      }
      {
        int r = idx >> 2, sl = idx & 3, g = sl ^ ((r >> 1) & 3);
        gload_lds16(Vg + (size_t)r * LL + g * 8, &vbuf[b][seg * 512]);
      }
    }
  };

  issue(0, 0);
  for (int kt = 0; kt < 49; ++kt) {
    __syncthreads();                   // tile kt resident; prev compute done
    if (kt + 1 < 49) issue(kt + 1, (kt + 1) & 1);
    const int b = kt & 1;
    const unsigned short* kb = &kbuf[b][0];
    const unsigned short* vbp = &vbuf[b][0];

    // S^T = K Q^T : A-frag key row = l31 (granule g = kc*2+half, slot = g ^ l31),
    // B-frag = qf. C layout: col = q = l31, row = key kr(r,half)=(r&3)+8*(r>>2)+4*half.
    f16v sc;
#pragma unroll
    for (int r = 0; r < 16; ++r) sc[r] = 0.f;
    __builtin_amdgcn_s_setprio(1);
#pragma unroll
    for (int kc = 0; kc < 16; ++kc) {
      int slot = (kc * 2 + half) ^ l31;
      bf8 kf = *(const bf8*)(kb + l31 * 256 + slot * 8);
      sc = mfma32(kf, qf[kc], sc);
    }
    __builtin_amdgcn_s_setprio(0);

    // Per 16-key chunk m: exp2 -> denominator tree -> cvtpk/permlane -> af[m].
    bf8 af[2];
#pragma unroll
    for (int m = 0; m < 2; ++m) {
      float p0 = __builtin_amdgcn_exp2f(sc[8 * m + 0]);
      float p1 = __builtin_amdgcn_exp2f(sc[8 * m + 1]);
      float p2 = __builtin_amdgcn_exp2f(sc[8 * m + 2]);
      float p3 = __builtin_amdgcn_exp2f(sc[8 * m + 3]);
      float p4 = __builtin_amdgcn_exp2f(sc[8 * m + 4]);
      float p5 = __builtin_amdgcn_exp2f(sc[8 * m + 5]);
      float p6 = __builtin_amdgcn_exp2f(sc[8 * m + 6]);
      float p7 = __builtin_amdgcn_exp2f(sc[8 * m + 7]);
      sden += ((p0 + p1) + (p2 + p3)) + ((p4 + p5) + (p6 + p7));
      int x0 = cvtpk_bf16(p0, p1);
      int y0 = cvtpk_bf16(p4, p5);
      int x1 = cvtpk_bf16(p2, p3);
      int y1 = cvtpk_bf16(p6, p7);
      asm("v_permlane32_swap_b32 %0, %1" : "+v"(x0), "+v"(y0));
      asm("v_permlane32_swap_b32 %0, %1" : "+v"(x1), "+v"(y1));
      i4 w;
      w[0] = x0; w[1] = x1; w[2] = y0; w[3] = y1;
      af[m] = *(bf8*)&w;
    }

    // O += P V : V row = t*32+l31 (ci), granule g = kc2*2+half, slot = g ^ ((l31>>1)&3)
    __builtin_amdgcn_s_setprio(1);
#pragma unroll
    for (int t = 0; t < 8; ++t) {
#pragma unroll
      for (int kc2 = 0; kc2 < 2; ++kc2) {
        int slot = (kc2 * 2 + half) ^ ((l31 >> 1) & 3);
        bf8 v = *(const bf8*)(vbp + (t * 32 + l31) * 32 + slot * 8);
        o[t] = mfma32(af[kc2], v, o[t]);
      }
    }
    __builtin_amdgcn_s_setprio(0);
  }

  // combine the two key-half partial denominators; lane l31 (both halves) holds den[row l31]
  sden += __shfl_xor(sden, 32);

  if (do_store) {
    if (lane < 32) denp[((size_t)ks * NB + n) * LL + q0 + l31] = sden;
    unsigned short* Ob = Opart + (((size_t)ks * NB + n) * LL + q0) * CIN;
#pragma unroll
    for (int t = 0; t < 8; ++t)
#pragma unroll
      for (int r = 0; r < 16; ++r) {
        int row = (r & 3) + 8 * (r >> 2) + 4 * half;
        Ob[(size_t)row * CIN + t * 32 + l31] = f2bf(o[t][r]);
      }
  }
}

// ---- kernel 3 v7: out = x + b_out + Wout @ ((O0+O1)/den), 128(c) x 112(L) tiles,
// 512 threads (8 waves, 4/SIMD). Per wave: 16c strip (w) x 112L; acc[7], 14 MFMA/chunk.
// 3136 = 112*28 exactly: no tail guards. Grid 896 (1.75 rounds of 512-block capacity).
__global__ __launch_bounds__(512, 4) void k_out(const unsigned short* O0, const unsigned short* O1,
    const unsigned short* Wo, const float* bout, const float* denp,
    const float* x, float* out) {
  __shared__ unsigned short wtile[2][8192];   // 128 c x 64 kci
  __shared__ unsigned short otile[2][7168];   // 112 L x 64 kci
  __shared__ float ivbuf[112];
  const int bid = blockIdx.x;
  const int n = bid & 7, t = bid >> 3;
  const int lt = t % 28, cth = t / 28;        // lt: 28 tiles of 112 L (exact); cth < 4
  const int tid = threadIdx.x;
  const int wave = tid >> 6, lane = tid & 63;
  const int quad = lane >> 4, c16 = lane & 15;

  const unsigned short* Wg = Wo + (size_t)(cth * 128) * CIN;
  const unsigned short* Og0 = O0 + ((size_t)n * LL + lt * 112) * CIN;
  const unsigned short* Og1 = O1 + ((size_t)n * LL + lt * 112) * CIN;

  auto issue = [&](int chunk, int b) {
    const int cb = (chunk & 3) * 64;
    const unsigned short* Og = chunk < 4 ? Og0 : Og1;
#pragma unroll
    for (int i = 0; i < 2; ++i) {              // 16 segs: 128 rows x 64 shorts
      int seg = i * 8 + wave;
      int p = seg * 64 + lane;
      int r = p >> 3, sl = p & 7, g = sl ^ (r & 7);
      gload_lds16(Wg + (size_t)r * CIN + cb + g * 8, &wtile[b][seg * 512]);
    }
#pragma unroll
    for (int i = 0; i < 2; ++i) {              // 14 segs: 112 rows x 64 shorts
      int seg = i * 8 + wave;
      if (seg < 14) {
        int p = seg * 64 + lane;
        int r = p >> 3, sl = p & 7, g = sl ^ (r & 7);
        gload_lds16(Og + (size_t)r * CIN + cb + g * 8, &otile[b][seg * 512]);
      }
    }
  };

  const f4 zz = {0.f, 0.f, 0.f, 0.f};
  f4 acc[7];
#pragma unroll
  for (int i = 0; i < 7; ++i) acc[i] = zz;

  issue(0, 0);
  // fused k_den: invden for this block's 112 L-rows (before first barrier)
  if (tid < 112) {
    int l = lt * 112 + tid;   // always < LL (exact tiling)
    ivbuf[tid] = 1.f / (denp[(size_t)n * LL + l] + denp[(size_t)(NB + n) * LL + l]);
  }
  for (int chunk = 0; chunk < 8; ++chunk) {
    __syncthreads();
    if (chunk + 1 < 8) issue(chunk + 1, (chunk + 1) & 1);
    const int bb = chunk & 1;
    __builtin_amdgcn_s_setprio(1);
#pragma unroll
    for (int kc = 0; kc < 2; ++kc) {
      const int slot = (kc * 4 + quad) ^ (c16 & 7);
      bf8 wf, ofr[7];
      wf = *(const bf8*)(&wtile[bb][(wave * 16 + c16) * 64 + slot * 8]);
#pragma unroll
      for (int nt = 0; nt < 7; ++nt)
        ofr[nt] = *(const bf8*)(&otile[bb][(nt * 16 + c16) * 64 + slot * 8]);
#pragma unroll
      for (int nt = 0; nt < 7; ++nt)
        acc[nt] = mfma_bf16(ofr[nt], wf, acc[nt]);
    }
    __builtin_amdgcn_s_setprio(0);
  }

  {
    const int c = cth * 128 + wave * 16 + c16;
    const float bv = bout[c];
#pragma unroll
    for (int nt = 0; nt < 7; ++nt) {
      int l = lt * 112 + nt * 16 + quad * 4;   // always < LL (exact tiling)
      f4 iv = *(const f4*)&ivbuf[nt * 16 + quad * 4];
      size_t base = ((size_t)n * CC + c) * LL + l;
      f4 xv = *(const f4*)(x + base);
      f4 r;
      r[0] = xv[0] + bv + acc[nt][0] * iv[0];
      r[1] = xv[1] + bv + acc[nt][1] * iv[1];
      r[2] = xv[2] + bv + acc[nt][2] * iv[2];
      r[3] = xv[3] + bv + acc[nt][3] * iv[3];
      *(f4*)(out + base) = r;
    }
  }
}

extern "C" void kernel_launch(void* const* d_in, const int* in_sizes, int n_in,
                              void* d_out, int out_size, void* d_ws, size_t ws_size,
                              hipStream_t stream) {
  const float* x     = (const float*)d_in[0];
  const float* W_g   = (const float*)d_in[1];
  const float* b_g   = (const float*)d_in[2];
  const float* W_th  = (const float*)d_in[3];
  const float* b_th  = (const float*)d_in[4];
  const float* W_ph  = (const float*)d_in[5];
  const float* b_ph  = (const float*)d_in[6];
  const float* W_out = (const float*)d_in[7];
  const float* b_out = (const float*)d_in[8];

  char* ws = (char*)d_ws;
  const size_t SZ_W  = 1048576;            // 4 x 131072 bf16
  const size_t SZ_P  = 12845056;           // 8*3136*256*2 bytes
  unsigned short* Wbf = (unsigned short*)(ws);
  unsigned short* QT  = (unsigned short*)(ws + SZ_W);
  unsigned short* KT  = (unsigned short*)(ws + SZ_W + SZ_P);
  unsigned short* Vb  = (unsigned short*)(ws + SZ_W + 2 * SZ_P);
  unsigned short* xT  = (unsigned short*)(ws + SZ_W + 3 * SZ_P);   // 2*SZ_P bytes
  unsigned short* O0  = xT;                 // alias: xT dead after k_proj
  unsigned short* O1  = (unsigned short*)(ws + SZ_W + 4 * SZ_P);
  float* denp   = (float*)(ws + SZ_W + 5 * SZ_P);                  // 2*NB*LL fp32
  float* out = (float*)d_out;

  k_cvt<<<5184, 256, 0, stream>>>(W_th, W_ph, W_g, W_out, Wbf, x, xT);
  k_proj<<<960, 512, 0, stream>>>(Wbf, b_th, b_ph, b_g, xT, QT, KT, Vb);
  k_attn<<<400, 256, 0, stream>>>(QT, KT, Vb, O0, denp);
  k_out<<<896, 512, 0, stream>>>(O0, O1, Wbf + 3 * 131072, b_out, denp, x, out);
}